// Round 8
// baseline (2934.603 us; speedup 1.0000x reference)
//
#include <hip/hip_runtime.h>

// NDDE forward-Euler, d=512, N=2000 — latency-bound on the per-step x
// all-to-all through the MALL (agent-scope atomics; only HW-verified
// coherent channel: R1/R4/R5). R8 = R7 + VMEM decluttering:
//   1. Weights REALLY register-resident: load * opaque runtime 1.0f, then
//      asm pin, plus waves_per_eu(1,1). (R5 pins-only -> scratch-split;
//      R7 budget-only -> remat. Need all three.)
//   2. out[] column stores buffered 16 steps in a static shift register,
//      flushed as 16-float line spans in the shadow (kills per-step RFO
//      line fetches from HBM that queued against polls/publish in vmcnt).
//   3. Ring protocol / y-history / reduction / depth-2 spin: as R7.

#define D     512
#define NTAU  100
#define M     112        // ring depth > delay span 101 + skew
#define HSLOT 101        // wave-private history depth
#define NW    64         // waves; wave w owns rows 8w..8w+7

typedef unsigned long long u64;

__device__ __forceinline__ float lo_f(u64 v){ union{unsigned u; float f;} c; c.u=(unsigned)v; return c.f; }
__device__ __forceinline__ u64 pack_rec(unsigned tag, float x){ union{unsigned u; float f;} c; c.f=x; return ((u64)tag<<32)|(u64)c.u; }
__device__ __forceinline__ u64 ag_ld(const u64* p){
    return __hip_atomic_load(p, __ATOMIC_RELAXED, __HIP_MEMORY_SCOPE_AGENT);
}
__device__ __forceinline__ void ag_st(u64* p, u64 v){
    __hip_atomic_store(p, v, __ATOMIC_RELAXED, __HIP_MEMORY_SCOPE_AGENT);
}
__device__ __forceinline__ void iss8(const u64* p, u64 r[8]){
    #pragma unroll
    for (int i = 0; i < 8; ++i) r[i] = ag_ld(p + 64 * i);
}
__device__ __forceinline__ bool chk8(const u64 r[8], unsigned t){
    bool ok = true;
    #pragma unroll
    for (int i = 0; i < 8; ++i) ok &= ((unsigned)(r[i] >> 32) == t);
    return __all(ok);
}
__device__ __forceinline__ float sel8(const float* a, int k){
    float s = a[0];
    s = (k == 1) ? a[1] : s;  s = (k == 2) ? a[2] : s;
    s = (k == 3) ? a[3] : s;  s = (k == 4) ? a[4] : s;
    s = (k == 5) ? a[5] : s;  s = (k == 6) ? a[6] : s;
    s = (k == 7) ? a[7] : s;
    return s;
}

__global__ __launch_bounds__(64)
__attribute__((amdgpu_waves_per_eu(1, 1)))
void ndde_r8(
    const float* __restrict__ x0p, const float* __restrict__ taup,
    const float* __restrict__ W1,  const float* __restrict__ W2,
    const float* __restrict__ bb,  const int* __restrict__ Np,
    float* __restrict__ out, u64* __restrict__ ring,
    float* __restrict__ hist, int use_hist, float one)
{
    const int lane    = threadIdx.x & 63;
    const int wb      = blockIdx.x;          // 0..63
    const int rowbase = wb * 8;
    const int N       = Np[0];
    const float dt    = 0.01f * taup[0];

    // ---- weights: 8 rows x 8 strided cols; scaled by opaque 1.0f + pinned ----
    float w1v[8][8], w2v[8][8];
    #pragma unroll
    for (int r = 0; r < 8; ++r){
        const float* p1 = W1 + (size_t)(rowbase + r) * D + lane;
        const float* p2 = W2 + (size_t)(rowbase + r) * D + lane;
        #pragma unroll
        for (int i = 0; i < 8; ++i){
            w1v[r][i] = p1[64 * i] * one;    // 2-inst chain: not remat-able
            w2v[r][i] = p2[64 * i] * one;
        }
    }
    #pragma unroll
    for (int r = 0; r < 8; ++r){
        #pragma unroll
        for (int i = 0; i < 8; ++i)
            asm volatile("" : "+v"(w1v[r][i]), "+v"(w2v[r][i]));  // opaque def
    }

    // ---- x0 partials: yp = W2*x0 (reused for all j <= 100) ----
    float xv0[8];
    #pragma unroll
    for (int i = 0; i < 8; ++i) xv0[i] = x0p[64 * i + lane];
    float yp[8], a[8];
    #pragma unroll
    for (int r = 0; r < 8; ++r){
        float sy = 0.f, st = 0.f;
        #pragma unroll
        for (int i = 0; i < 8; ++i){
            sy = fmaf(w2v[r][i], xv0[i], sy);
            st = fmaf(w1v[r][i], xv0[i], st);
        }
        yp[r] = sy; a[r] = st + sy;
    }

    // ---- reduction: low-bit butterfly -> reg select -> high-bit butterfly ----
    const int sel = lane & 7;
    #pragma unroll
    for (int r = 0; r < 8; ++r){
        a[r] += __shfl_xor(a[r], 1, 64);
        a[r] += __shfl_xor(a[r], 2, 64);
        a[r] += __shfl_xor(a[r], 4, 64);
    }
    float d0 = sel8(a, sel);
    d0 += __shfl_xor(d0, 8, 64);
    d0 += __shfl_xor(d0, 16, 64);
    d0 += __shfl_xor(d0, 32, 64);

    // ---- step 0 local; publish x_1 (tag 2); cols 0,1 written directly ----
    float xloc = 0.f, bval = 0.f;
    if (lane < 8){
        const int row = rowbase + lane;
        xloc = x0p[row];
        bval = bb[row];
        out[(size_t)row * (N + 1)] = xloc;
        if (N >= 1){
            const float x1 = xloc + dt * tanhf(d0 + bval);
            xloc = x1;
            ag_st(ring + D + row, pack_rec(2u, x1));
            out[(size_t)row * (N + 1) + 1] = x1;
        }
    }

    float* myh = hist + (size_t)wb * HSLOT * D;   // wave-private history

    u64 xa[8], xb[8];
    float xf[8];
    float obuf[16];                // out-column shift register (static idx only)
    #pragma unroll
    for (int k = 0; k < 16; ++k) obuf[k] = 0.f;
    int sx = 1, sp = 2, syr = 1;   // ring slots: j%M, (j+1)%M, (j-100)%M
    int hw = 0, hr = 0;            // history write/read slots
    bool dead = false;

    for (int j = 1; j < N && !dead; ++j){
        const bool needy  = (j > NTAU);
        const unsigned tx = (unsigned)(j + 1);
        const u64* px = ring + (size_t)sx * D + lane;

        // ---- fallback path only: agent y before the x-spin ----
        u64 yr[8];
        if (!use_hist && needy){
            const u64* py = ring + (size_t)syr * D + lane;
            iss8(py, yr);
        }

        // ---- depth-2 pipelined spin for x_j ----
        iss8(px, xa);
        int it = 0;
        for (;;){
            iss8(px, xb);
            if (chk8(xa, tx)) break;
            iss8(px, xa);
            if (chk8(xb, tx)){
                #pragma unroll
                for (int i = 0; i < 8; ++i) xa[i] = xb[i];
                break;
            }
            if ((it += 2) > (1 << 21)){ dead = true; break; }
        }
        #pragma unroll
        for (int i = 0; i < 8; ++i) xf[i] = lo_f(xa[i]);

        // ---- fallback path only: verify y, recompute yp on mismatch ----
        if (!use_hist && needy){
            const unsigned ty = (unsigned)(j - NTAU + 1);
            if (!chk8(yr, ty)){
                const u64* py = ring + (size_t)syr * D + lane;
                int it2 = 0;
                for (;;){
                    iss8(py, yr);
                    if (chk8(yr, ty)) break;
                    if (++it2 > (1 << 21)){ dead = true; break; }
                }
            }
            #pragma unroll
            for (int r = 0; r < 8; ++r){
                float sy = 0.f;
                #pragma unroll
                for (int i = 0; i < 8; ++i) sy = fmaf(w2v[r][i], lo_f(yr[i]), sy);
                yp[r] = sy;
            }
        }

        // ---- critical path: 64 FMA + reduction + integrate + ring publish ----
        #pragma unroll
        for (int r = 0; r < 8; ++r){
            float s = yp[r];
            #pragma unroll
            for (int i = 0; i < 8; ++i) s = fmaf(w1v[r][i], xf[i], s);
            a[r] = s;
        }
        #pragma unroll
        for (int r = 0; r < 8; ++r){
            a[r] += __shfl_xor(a[r], 1, 64);
            a[r] += __shfl_xor(a[r], 2, 64);
            a[r] += __shfl_xor(a[r], 4, 64);
        }
        float dd = sel8(a, sel);
        dd += __shfl_xor(dd, 8, 64);
        dd += __shfl_xor(dd, 16, 64);
        dd += __shfl_xor(dd, 32, 64);

        if (lane < 8){
            const float xn = xloc + dt * tanhf(dd + bval);
            xloc = xn;
            const int row = rowbase + lane;
            ag_st(ring + (size_t)sp * D + row, pack_rec(tx + 1, xn));

            // ---- shadow: out shift-register + every-16-step line flush ----
            #pragma unroll
            for (int k = 0; k < 15; ++k) obuf[k] = obuf[k + 1];
            obuf[15] = xn;
            if (((j - 1) & 15) == 15){            // buffer holds cols j-14..j+1
                float* po = out + (size_t)row * (N + 1) + (j - 14);
                #pragma unroll
                for (int k = 0; k < 16; ++k) po[k] = obuf[k];
            }
        }

        // ---- shadow: history write + next-step y partial ----
        if (use_hist){
            float* hwp = myh + (size_t)hw * D + lane;
            #pragma unroll
            for (int i = 0; i < 8; ++i) hwp[64 * i] = xf[i];
            if (j >= NTAU){            // step j+1 needs y = x_{j-99}
                const float* hrp = myh + (size_t)hr * D + lane;
                float yv[8];
                #pragma unroll
                for (int i = 0; i < 8; ++i) yv[i] = hrp[64 * i];
                #pragma unroll
                for (int r = 0; r < 8; ++r){
                    float sy = 0.f;
                    #pragma unroll
                    for (int i = 0; i < 8; ++i) sy = fmaf(w2v[r][i], yv[i], sy);
                    yp[r] = sy;
                }
                hr = (hr == HSLOT - 1) ? 0 : hr + 1;
            }
            hw = (hw == HSLOT - 1) ? 0 : hw + 1;
        }

        sx = (sx == M - 1) ? 0 : sx + 1;
        sp = (sp == M - 1) ? 0 : sp + 1;
        if (j >= NTAU + 1) syr = (syr == M - 1) ? 0 : syr + 1;
    }

    // ---- tail flush: cnt = values buffered since last flush ----
    if (N >= 2 && lane < 8){
        const int cnt = ((N - 2) & 15) + 1;      // 1..16
        const int row = rowbase + lane;
        float* po = out + (size_t)row * (N + 1);
        #pragma unroll
        for (int k = 0; k < 16; ++k){
            if (k >= 16 - cnt) po[N - 15 + k] = obuf[k];
        }
    }
}

extern "C" void kernel_launch(void* const* d_in, const int* in_sizes, int n_in,
                              void* d_out, int out_size, void* d_ws, size_t ws_size,
                              hipStream_t stream)
{
    const float* x0  = (const float*)d_in[0];
    const float* tau = (const float*)d_in[1];
    const float* W1  = (const float*)d_in[2];
    const float* W2  = (const float*)d_in[3];
    const float* b   = (const float*)d_in[4];
    const int*   Np  = (const int*)  d_in[5];

    // d_ws layout: ring [0, M*D*8); wave-private history after.
    // No memset needed: ring tags are 1..N+1; 0xAA poison never matches.
    const size_t ring_bytes = (size_t)M * D * 8;
    const size_t hist_bytes = (size_t)NW * HSLOT * D * 4;
    const int use_hist = (ws_size >= ring_bytes + hist_bytes) ? 1 : 0;

    u64*   ring = (u64*)d_ws;
    float* hist = (float*)((char*)d_ws + ring_bytes);
    const float one = 1.0f;    // runtime-opaque weight scale (residency lever)

    hipLaunchKernelGGL(ndde_r8, dim3(NW), dim3(64), 0, stream,
                       x0, tau, W1, W2, b, Np, (float*)d_out, ring, hist, use_hist, one);
}